// Round 2
// baseline (89.702 us; speedup 1.0000x reference)
//
#include <hip/hip_runtime.h>
#include <hip/hip_bf16.h>

#define N_ROWS 8192
#define DIM    128
#define NCLASS 512
#define MARGIN 0.3f

typedef unsigned short u16;
typedef __attribute__((ext_vector_type(8))) short bf16x8;
typedef __attribute__((ext_vector_type(4))) float f32x4;

__device__ inline void load_lds16(const u16* g, u16* l) {
    __builtin_amdgcn_global_load_lds((const __attribute__((address_space(1))) void*)g,
                                     (__attribute__((address_space(3))) void*)l, 16, 0, 0);
}

// ---------------- init: zero neg_bits + hist ----------------
__global__ void k_init(unsigned* neg_bits, int* hist) {
    int i = blockIdx.x * 256 + threadIdx.x;
    if (i < N_ROWS) neg_bits[i] = 0u;
    if (i < NCLASS) hist[i] = 0;
}

// ---------------- normalize rows, emit f32 + bf16, histogram labels ----------------
__global__ void k_prep(const float* __restrict__ feat, const int* __restrict__ lab,
                       float* __restrict__ fn, u16* __restrict__ fb, int* __restrict__ hist) {
    int w = threadIdx.x >> 6, lane = threadIdx.x & 63;
    int row = blockIdx.x * 4 + w;
    float2 v = *reinterpret_cast<const float2*>(feat + row * DIM + lane * 2);
    float ss = v.x * v.x + v.y * v.y;
    #pragma unroll
    for (int off = 32; off; off >>= 1) ss += __shfl_xor(ss, off);
    float r = 1.0f / fmaxf(sqrtf(ss), 1e-12f);
    float x = v.x * r, y = v.y * r;
    *reinterpret_cast<float2*>(fn + row * DIM + lane * 2) = make_float2(x, y);
    __hip_bfloat16 bx = __float2bfloat16(x), by = __float2bfloat16(y);
    u16 ux = *reinterpret_cast<u16*>(&bx), uy = *reinterpret_cast<u16*>(&by);
    ushort2 p; p.x = ux; p.y = uy;
    *reinterpret_cast<ushort2*>(fb + row * DIM + lane * 2) = p;
    if (lane == 0) atomicAdd(&hist[lab[row]], 1);
}

// ---------------- class sums S_c = sum of normalized rows of class c ----------------
__global__ void k_clsum(const int* __restrict__ lab, const float* __restrict__ fn,
                        float* __restrict__ cs) {
    __shared__ int s_cnt;
    __shared__ int s_idx[96];
    int t = threadIdx.x, c = blockIdx.x;
    if (t == 0) s_cnt = 0;
    __syncthreads();
    for (int r = t; r < N_ROWS; r += 256)
        if (lab[r] == c) { int p = atomicAdd(&s_cnt, 1); if (p < 96) s_idx[p] = r; }
    __syncthreads();
    int cnt = s_cnt > 96 ? 96 : s_cnt;
    if (t < DIM) {
        float a = 0.f;
        for (int p = 0; p < cnt; ++p) a += fn[s_idx[p] * DIM + t];
        cs[c * DIM + t] = a;
    }
}

// ---------------- pos_dot[i] = f_i . S_{c(i)}  (f32 path, exact-ish) ----------------
__global__ void k_posdot(const float* __restrict__ fn, const float* __restrict__ cs,
                         const int* __restrict__ lab, float* __restrict__ pd) {
    int w = threadIdx.x >> 6, lane = threadIdx.x & 63;
    int row = blockIdx.x * 4 + w;
    int c = lab[row];
    float2 a = *reinterpret_cast<const float2*>(fn + row * DIM + lane * 2);
    float2 b = *reinterpret_cast<const float2*>(cs + c * DIM + lane * 2);
    float s = a.x * b.x + a.y * b.y;
    #pragma unroll
    for (int off = 32; off; off >>= 1) s += __shfl_xor(s, off);
    if (lane == 0) pd[row] = s;
}

// ---------------- main: fused sim-GEMM + masked neg-max ----------------
// grid (64 row-panels, 8 j-chunks); block 256 = 4 waves (2x2), wave tile 64x64,
// 16x16x32 bf16 MFMA, 4x4 fragments. A in registers (full K=128); B staged in LDS
// via global_load_lds w/ XOR-swizzled source (linear LDS dest).
__global__ __launch_bounds__(256) void k_main(const u16* __restrict__ fb,
                                              const int* __restrict__ lab,
                                              unsigned* __restrict__ neg_bits) {
    __shared__ u16 Bt[128 * 128];
    __shared__ float red[2][128];
    const int t = threadIdx.x;
    const int lane = t & 63, w = t >> 6;
    const int wr = w >> 1, wc = w & 1;
    const int i0 = blockIdx.x * 128;
    const int jbase = blockIdx.y * 1024;
    const int l15 = lane & 15, l4 = lane >> 4;

    // A fragments: a[m][ks], row = i0 + wr*64 + m*16 + (lane&15), k = ks*32 + (lane>>4)*8
    bf16x8 a[4][4];
    #pragma unroll
    for (int m = 0; m < 4; ++m)
        #pragma unroll
        for (int ks = 0; ks < 4; ++ks)
            a[m][ks] = *reinterpret_cast<const bf16x8*>(
                fb + (i0 + wr * 64 + m * 16 + l15) * DIM + ks * 32 + l4 * 8);

    // labels for the output rows this lane owns: row = m*16 + (lane>>4)*4 + rg
    int labr[4][4];
    #pragma unroll
    for (int m = 0; m < 4; ++m)
        #pragma unroll
        for (int rg = 0; rg < 4; ++rg)
            labr[m][rg] = lab[i0 + wr * 64 + m * 16 + l4 * 4 + rg];

    float negp[4][4];
    #pragma unroll
    for (int m = 0; m < 4; ++m)
        #pragma unroll
        for (int rg = 0; rg < 4; ++rg) negp[m][rg] = -1e9f;

    for (int jt = 0; jt < 8; ++jt) {
        const int j0 = jbase + jt * 128;
        // stage B tile (128 rows x 128 k, bf16) — source-swizzled, linear LDS
        #pragma unroll
        for (int it = 0; it < 8; ++it) {
            int q = it * 256 + t;           // 16B chunk id
            int brow = q >> 4, kb = q & 15;
            load_lds16(fb + (j0 + brow) * DIM + ((kb ^ (brow & 7)) * 8), Bt + q * 8);
        }
        __syncthreads();

        // column labels: col = wc*64 + n*16 + (lane&15)  [FIX: include wc*64]
        int labc[4];
        #pragma unroll
        for (int n = 0; n < 4; ++n) labc[n] = lab[j0 + wc * 64 + n * 16 + l15];

        f32x4 acc[4][4];
        #pragma unroll
        for (int m = 0; m < 4; ++m)
            #pragma unroll
            for (int n = 0; n < 4; ++n) acc[m][n] = f32x4{0.f, 0.f, 0.f, 0.f};

        #pragma unroll
        for (int ks = 0; ks < 4; ++ks) {
            bf16x8 b[4];
            #pragma unroll
            for (int n = 0; n < 4; ++n) {
                int brow = wc * 64 + n * 16 + l15;
                int kb = ks * 4 + l4;
                b[n] = *reinterpret_cast<const bf16x8*>(
                    Bt + brow * DIM + ((kb ^ (brow & 7)) * 8));
            }
            #pragma unroll
            for (int m = 0; m < 4; ++m)
                #pragma unroll
                for (int n = 0; n < 4; ++n)
                    acc[m][n] = __builtin_amdgcn_mfma_f32_16x16x32_bf16(a[m][ks], b[n],
                                                                        acc[m][n], 0, 0, 0);
        }

        // masked neg-max epilogue: col = wc*64 + n*16 + (lane&15)
        #pragma unroll
        for (int m = 0; m < 4; ++m)
            #pragma unroll
            for (int n = 0; n < 4; ++n) {
                int lc = labc[n];
                #pragma unroll
                for (int rg = 0; rg < 4; ++rg) {
                    float s = acc[m][n][rg];
                    float v = (labr[m][rg] != lc) ? s : -1e9f;
                    negp[m][rg] = fmaxf(negp[m][rg], v);
                }
            }
        __syncthreads();   // Bt reused next iteration
    }

    // per-row reduce across the 16 lanes (cols) sharing each row
    #pragma unroll
    for (int m = 0; m < 4; ++m)
        #pragma unroll
        for (int rg = 0; rg < 4; ++rg) {
            float v = negp[m][rg];
            v = fmaxf(v, __shfl_xor(v, 1));
            v = fmaxf(v, __shfl_xor(v, 2));
            v = fmaxf(v, __shfl_xor(v, 4));
            v = fmaxf(v, __shfl_xor(v, 8));
            negp[m][rg] = v;
        }
    if (l15 == 0) {
        #pragma unroll
        for (int m = 0; m < 4; ++m)
            #pragma unroll
            for (int rg = 0; rg < 4; ++rg)
                red[wc][wr * 64 + m * 16 + l4 * 4 + rg] = negp[m][rg];
    }
    __syncthreads();
    if (t < 128) {
        float v = fmaxf(red[0][t], red[1][t]);
        if (v > -1e8f)
            atomicMax(&neg_bits[i0 + t], __float_as_uint(v + 2.0f));  // v+2 > 0 -> uint-monotone
    }
}

// ---------------- finalize: loss = mean(relu(margin + neg - pos)) ----------------
__global__ void k_final(const float* __restrict__ pd, const unsigned* __restrict__ nb,
                        const int* __restrict__ lab, const int* __restrict__ hist,
                        float* __restrict__ out) {
    int t = threadIdx.x;
    float acc = 0.f;
    for (int r = t; r < N_ROWS; r += 256) {
        unsigned u = nb[r];
        float neg = u ? (__uint_as_float(u) - 2.0f) : 0.0f;
        int cnt = hist[lab[r]] - 1;                    // positives excluding self
        float pos = cnt > 0 ? (pd[r] - 1.0f) / (float)cnt : 0.0f;
        acc += fmaxf(0.0f, MARGIN + neg - pos);
    }
    #pragma unroll
    for (int off = 32; off; off >>= 1) acc += __shfl_xor(acc, off);
    __shared__ float s[4];
    if ((t & 63) == 0) s[t >> 6] = acc;
    __syncthreads();
    if (t == 0) out[0] = (s[0] + s[1] + s[2] + s[3]) / (float)N_ROWS;
}

extern "C" void kernel_launch(void* const* d_in, const int* in_sizes, int n_in,
                              void* d_out, int out_size, void* d_ws, size_t ws_size,
                              hipStream_t stream) {
    const float* feat = (const float*)d_in[0];
    const int* lab    = (const int*)d_in[1];
    char* ws = (char*)d_ws;
    float*    fn   = (float*)ws;                               // 4 MB
    u16*      fb   = (u16*)(ws + (4u << 20));                  // 2 MB
    float*    cs   = (float*)(ws + (6u << 20));                // 256 KB
    float*    pd   = (float*)(ws + (6u << 20) + (256u << 10)); // 32 KB
    unsigned* nb   = (unsigned*)(ws + (6u << 20) + (288u << 10)); // 32 KB
    int*      hist = (int*)(ws + (6u << 20) + (320u << 10));   // 2 KB
    float*    out  = (float*)d_out;

    k_init  <<<32,   256, 0, stream>>>(nb, hist);
    k_prep  <<<2048, 256, 0, stream>>>(feat, lab, fn, fb, hist);
    k_clsum <<<512,  256, 0, stream>>>(lab, fn, cs);
    k_posdot<<<2048, 256, 0, stream>>>(fn, cs, lab, pd);
    k_main  <<<dim3(64, 8), 256, 0, stream>>>(fb, lab, nb);
    k_final <<<1,    256, 0, stream>>>(pd, nb, lab, hist, out);
}

// Round 3
// 70.901 us; speedup vs baseline: 1.2652x; 1.2652x over previous
//
#include <hip/hip_runtime.h>
#include <hip/hip_bf16.h>

#define N_ROWS 8192
#define DIM    128
#define NCLASS 512
#define MARGIN 0.3f

typedef unsigned short u16;
typedef __attribute__((ext_vector_type(8))) short bf16x8;
typedef __attribute__((ext_vector_type(4))) float f32x4;

__device__ inline void load_lds16(const u16* g, u16* l) {
    __builtin_amdgcn_global_load_lds((const __attribute__((address_space(1))) void*)g,
                                     (__attribute__((address_space(3))) void*)l, 16, 0, 0);
}

// ---------------- normalize rows, emit f32 + bf16, histogram labels ----------------
__global__ void k_prep(const float* __restrict__ feat, const int* __restrict__ lab,
                       float* __restrict__ fn, u16* __restrict__ fb, int* __restrict__ hist) {
    int w = threadIdx.x >> 6, lane = threadIdx.x & 63;
    int row = blockIdx.x * 4 + w;
    float2 v = *reinterpret_cast<const float2*>(feat + row * DIM + lane * 2);
    float ss = v.x * v.x + v.y * v.y;
    #pragma unroll
    for (int off = 32; off; off >>= 1) ss += __shfl_xor(ss, off);
    float r = 1.0f / fmaxf(sqrtf(ss), 1e-12f);
    float x = v.x * r, y = v.y * r;
    *reinterpret_cast<float2*>(fn + row * DIM + lane * 2) = make_float2(x, y);
    __hip_bfloat16 bx = __float2bfloat16(x), by = __float2bfloat16(y);
    u16 ux = *reinterpret_cast<u16*>(&bx), uy = *reinterpret_cast<u16*>(&by);
    ushort2 p; p.x = ux; p.y = uy;
    *reinterpret_cast<ushort2*>(fb + row * DIM + lane * 2) = p;
    if (lane == 0) atomicAdd(&hist[lab[row]], 1);
}

// ---------------- class sums S_c (one block per class, int4 label scan) ----------------
__global__ void k_clsum(const int* __restrict__ lab, const float* __restrict__ fn,
                        float* __restrict__ cs) {
    __shared__ int s_cnt;
    __shared__ int s_idx[128];
    int t = threadIdx.x, c = blockIdx.x;
    if (t == 0) s_cnt = 0;
    __syncthreads();
    for (int q = t; q < N_ROWS / 4; q += 256) {
        int4 L = reinterpret_cast<const int4*>(lab)[q];
        if (L.x == c) { int p = atomicAdd(&s_cnt, 1); if (p < 128) s_idx[p] = q * 4 + 0; }
        if (L.y == c) { int p = atomicAdd(&s_cnt, 1); if (p < 128) s_idx[p] = q * 4 + 1; }
        if (L.z == c) { int p = atomicAdd(&s_cnt, 1); if (p < 128) s_idx[p] = q * 4 + 2; }
        if (L.w == c) { int p = atomicAdd(&s_cnt, 1); if (p < 128) s_idx[p] = q * 4 + 3; }
    }
    __syncthreads();
    int cnt = s_cnt < 128 ? s_cnt : 128;
    if (t < DIM) {
        float a0 = 0.f, a1 = 0.f, a2 = 0.f, a3 = 0.f;
        int p = 0;
        for (; p + 4 <= cnt; p += 4) {
            a0 += fn[s_idx[p + 0] * DIM + t];
            a1 += fn[s_idx[p + 1] * DIM + t];
            a2 += fn[s_idx[p + 2] * DIM + t];
            a3 += fn[s_idx[p + 3] * DIM + t];
        }
        for (; p < cnt; ++p) a0 += fn[s_idx[p] * DIM + t];
        cs[c * DIM + t] = (a0 + a1) + (a2 + a3);
    }
}

// ---------------- main: fused sim-GEMM + masked neg-max ----------------
// grid (32 i-panels, 16 j-chunks); 512 threads = 8 waves (4 wr x 2 wc), wave tile 64x64.
// i-panel 256 rows, j-chunk 512 cols = 4 j-tiles of 128. Double-buffered B staging
// (global_load_lds, source-XOR-swizzled, linear LDS dest), one barrier per tile.
__global__ __launch_bounds__(512) void k_main(const u16* __restrict__ fb,
                                              const int* __restrict__ lab,
                                              unsigned* __restrict__ neg_bits) {
    __shared__ u16 Bt[2][128 * 128];      // 64 KB
    __shared__ float red[2][256];         // 2 KB
    const int t = threadIdx.x;
    const int lane = t & 63, w = t >> 6;
    const int wr = w >> 1, wc = w & 1;    // wr 0..3, wc 0..1
    const int i0 = blockIdx.x * 256;
    const int jbase = blockIdx.y * 512;
    const int l15 = lane & 15, l4 = lane >> 4;

    auto stage = [&](int jt, int buf) {
        const int j0 = jbase + jt * 128;
        #pragma unroll
        for (int it = 0; it < 4; ++it) {
            int q = it * 512 + t;                 // 16B chunk id, 2048 total
            int brow = q >> 4, kb = q & 15;
            load_lds16(fb + (j0 + brow) * DIM + ((kb ^ (brow & 7)) * 8),
                       &Bt[buf][q * 8]);
        }
    };

    // A fragments: row = i0 + wr*64 + m*16 + l15, k = ks*32 + l4*8
    bf16x8 a[4][4];
    #pragma unroll
    for (int m = 0; m < 4; ++m)
        #pragma unroll
        for (int ks = 0; ks < 4; ++ks)
            a[m][ks] = *reinterpret_cast<const bf16x8*>(
                fb + (i0 + wr * 64 + m * 16 + l15) * DIM + ks * 32 + l4 * 8);

    // output-row labels: row = i0 + wr*64 + m*16 + l4*4 + rg
    int labr[4][4];
    #pragma unroll
    for (int m = 0; m < 4; ++m)
        #pragma unroll
        for (int rg = 0; rg < 4; ++rg)
            labr[m][rg] = lab[i0 + wr * 64 + m * 16 + l4 * 4 + rg];

    // column labels for all 4 j-tiles: col = jbase + jt*128 + wc*64 + n*16 + l15
    int labc[4][4];
    #pragma unroll
    for (int jt = 0; jt < 4; ++jt)
        #pragma unroll
        for (int n = 0; n < 4; ++n)
            labc[jt][n] = lab[jbase + jt * 128 + wc * 64 + n * 16 + l15];

    float negp[4][4];
    #pragma unroll
    for (int m = 0; m < 4; ++m)
        #pragma unroll
        for (int rg = 0; rg < 4; ++rg) negp[m][rg] = -1e9f;

    stage(0, 0);
    __syncthreads();   // compiler emits vmcnt(0) drain before barrier

    #pragma unroll
    for (int jt = 0; jt < 4; ++jt) {
        const int cb = jt & 1;
        if (jt < 3) stage(jt + 1, cb ^ 1);   // prefetch next tile (hidden under compute)

        f32x4 acc[4][4];
        #pragma unroll
        for (int m = 0; m < 4; ++m)
            #pragma unroll
            for (int n = 0; n < 4; ++n) acc[m][n] = f32x4{0.f, 0.f, 0.f, 0.f};

        #pragma unroll
        for (int ks = 0; ks < 4; ++ks) {
            bf16x8 b[4];
            #pragma unroll
            for (int n = 0; n < 4; ++n) {
                int brow = wc * 64 + n * 16 + l15;
                int kb = ks * 4 + l4;
                b[n] = *reinterpret_cast<const bf16x8*>(
                    &Bt[cb][brow * DIM + ((kb ^ (brow & 7)) * 8)]);
            }
            #pragma unroll
            for (int m = 0; m < 4; ++m)
                #pragma unroll
                for (int n = 0; n < 4; ++n)
                    acc[m][n] = __builtin_amdgcn_mfma_f32_16x16x32_bf16(a[m][ks], b[n],
                                                                        acc[m][n], 0, 0, 0);
        }

        // masked neg-max epilogue: col label from preloaded regs
        #pragma unroll
        for (int m = 0; m < 4; ++m)
            #pragma unroll
            for (int n = 0; n < 4; ++n) {
                int lc = labc[jt][n];
                #pragma unroll
                for (int rg = 0; rg < 4; ++rg) {
                    float s = acc[m][n][rg];
                    float v = (labr[m][rg] != lc) ? s : -1e9f;
                    negp[m][rg] = fmaxf(negp[m][rg], v);
                }
            }
        __syncthreads();   // drains prefetch + protects Bt[cb] for overwrite
    }

    // per-row reduce across the 16 lanes (cols) sharing each row
    #pragma unroll
    for (int m = 0; m < 4; ++m)
        #pragma unroll
        for (int rg = 0; rg < 4; ++rg) {
            float v = negp[m][rg];
            v = fmaxf(v, __shfl_xor(v, 1));
            v = fmaxf(v, __shfl_xor(v, 2));
            v = fmaxf(v, __shfl_xor(v, 4));
            v = fmaxf(v, __shfl_xor(v, 8));
            negp[m][rg] = v;
        }
    if (l15 == 0) {
        #pragma unroll
        for (int m = 0; m < 4; ++m)
            #pragma unroll
            for (int rg = 0; rg < 4; ++rg)
                red[wc][wr * 64 + m * 16 + l4 * 4 + rg] = negp[m][rg];
    }
    __syncthreads();
    if (t < 256) {
        float v = fmaxf(red[0][t], red[1][t]);
        if (v > -1e8f)
            atomicMax(&neg_bits[i0 + t], __float_as_uint(v + 2.0f));  // v+2 > 0 -> uint-monotone
    }
}

// ---------------- fused posdot + loss partial (64 blocks) ----------------
__global__ void k_loss(const float* __restrict__ fn, const float* __restrict__ cs,
                       const int* __restrict__ lab, const unsigned* __restrict__ nb,
                       const int* __restrict__ hist, float* __restrict__ lacc) {
    int t = threadIdx.x, lane = t & 63, w = t >> 6;
    int rbase = blockIdx.x * 128 + w * 32;
    int half = lane >> 5;             // 2 rows per wave-iteration
    int d0 = (lane & 31) * 4;
    float acc = 0.f;
    #pragma unroll
    for (int k = 0; k < 16; ++k) {
        int row = rbase + k * 2 + half;
        int c = lab[row];
        float4 x = *reinterpret_cast<const float4*>(fn + row * DIM + d0);
        float4 y = *reinterpret_cast<const float4*>(cs + c * DIM + d0);
        float s = x.x * y.x + x.y * y.y + x.z * y.z + x.w * y.w;
        s += __shfl_xor(s, 16); s += __shfl_xor(s, 8);
        s += __shfl_xor(s, 4);  s += __shfl_xor(s, 2); s += __shfl_xor(s, 1);
        if ((lane & 31) == 0) {
            unsigned u = nb[row];
            float neg = u ? (__uint_as_float(u) - 2.0f) : 0.0f;
            int cnt = hist[c] - 1;
            float pos = cnt > 0 ? (s - 1.0f) / (float)cnt : 0.0f;
            acc += fmaxf(0.0f, MARGIN + neg - pos);
        }
    }
    #pragma unroll
    for (int off = 32; off; off >>= 1) acc += __shfl_xor(acc, off);
    __shared__ float sm[4];
    if (lane == 0) sm[w] = acc;
    __syncthreads();
    if (t == 0) atomicAdd(lacc, (sm[0] + sm[1]) + (sm[2] + sm[3]));
}

// ---------------- final scalar ----------------
__global__ void k_out(const float* __restrict__ lacc, float* __restrict__ out) {
    if (threadIdx.x == 0) out[0] = lacc[0] * (1.0f / (float)N_ROWS);
}

extern "C" void kernel_launch(void* const* d_in, const int* in_sizes, int n_in,
                              void* d_out, int out_size, void* d_ws, size_t ws_size,
                              hipStream_t stream) {
    const float* feat = (const float*)d_in[0];
    const int* lab    = (const int*)d_in[1];
    char* ws = (char*)d_ws;
    float*    fn   = (float*)ws;                                   // 4 MB
    u16*      fb   = (u16*)(ws + (4u << 20));                      // 2 MB
    char*     zr   = ws + (6u << 20);                              // zeroed region:
    float*    cs   = (float*)zr;                                   //   256 KB
    unsigned* nb   = (unsigned*)(zr + (256u << 10));               //   32 KB
    int*      hist = (int*)(zr + (288u << 10));                    //   2 KB
    float*    lacc = (float*)(zr + (290u << 10));                  //   4 B
    float*    out  = (float*)d_out;

    hipMemsetAsync(zr, 0, (291u << 10), stream);
    k_prep  <<<2048, 256, 0, stream>>>(feat, lab, fn, fb, hist);
    k_clsum <<<512,  256, 0, stream>>>(lab, fn, cs);
    k_main  <<<dim3(32, 16), 512, 0, stream>>>(fb, lab, nb);
    k_loss  <<<64,   256, 0, stream>>>(fn, cs, lab, nb, hist, lacc);
    k_out   <<<1,    64,  0, stream>>>(lacc, out);
}

// Round 4
// 64.531 us; speedup vs baseline: 1.3901x; 1.0987x over previous
//
#include <hip/hip_runtime.h>
#include <hip/hip_bf16.h>

#define N_ROWS 8192
#define DIM    128
#define NCLASS 512
#define MARGIN 0.3f

typedef unsigned short u16;
typedef __attribute__((ext_vector_type(8))) short bf16x8;
typedef __attribute__((ext_vector_type(4))) float f32x4;

__device__ inline void load_lds16(const u16* g, u16* l) {
    __builtin_amdgcn_global_load_lds((const __attribute__((address_space(1))) void*)g,
                                     (__attribute__((address_space(3))) void*)l, 16, 0, 0);
}

// ---------------- normalize rows, emit f32 + bf16 ----------------
__global__ void k_prep(const float* __restrict__ feat, float* __restrict__ fn,
                       u16* __restrict__ fb) {
    int w = threadIdx.x >> 6, lane = threadIdx.x & 63;
    int row = blockIdx.x * 4 + w;
    float2 v = *reinterpret_cast<const float2*>(feat + row * DIM + lane * 2);
    float ss = v.x * v.x + v.y * v.y;
    #pragma unroll
    for (int off = 32; off; off >>= 1) ss += __shfl_xor(ss, off);
    float r = 1.0f / fmaxf(sqrtf(ss), 1e-12f);
    float x = v.x * r, y = v.y * r;
    *reinterpret_cast<float2*>(fn + row * DIM + lane * 2) = make_float2(x, y);
    __hip_bfloat16 bx = __float2bfloat16(x), by = __float2bfloat16(y);
    u16 ux = *reinterpret_cast<u16*>(&bx), uy = *reinterpret_cast<u16*>(&by);
    ushort2 p; p.x = ux; p.y = uy;
    *reinterpret_cast<ushort2*>(fb + row * DIM + lane * 2) = p;
}

// ---------------- class sums S_c + per-class histogram ----------------
__global__ void k_clsum(const int* __restrict__ lab, const float* __restrict__ fn,
                        float* __restrict__ cs, int* __restrict__ hist) {
    __shared__ int s_cnt;
    __shared__ int s_idx[128];
    int t = threadIdx.x, c = blockIdx.x;
    if (t == 0) s_cnt = 0;
    __syncthreads();
    for (int q = t; q < N_ROWS / 4; q += 256) {
        int4 L = reinterpret_cast<const int4*>(lab)[q];
        if (L.x == c) { int p = atomicAdd(&s_cnt, 1); if (p < 128) s_idx[p] = q * 4 + 0; }
        if (L.y == c) { int p = atomicAdd(&s_cnt, 1); if (p < 128) s_idx[p] = q * 4 + 1; }
        if (L.z == c) { int p = atomicAdd(&s_cnt, 1); if (p < 128) s_idx[p] = q * 4 + 2; }
        if (L.w == c) { int p = atomicAdd(&s_cnt, 1); if (p < 128) s_idx[p] = q * 4 + 3; }
    }
    __syncthreads();
    if (t == 0) hist[c] = s_cnt;
    int cnt = s_cnt < 128 ? s_cnt : 128;
    if (t < DIM) {
        float a0 = 0.f, a1 = 0.f, a2 = 0.f, a3 = 0.f;
        int p = 0;
        for (; p + 4 <= cnt; p += 4) {
            a0 += fn[s_idx[p + 0] * DIM + t];
            a1 += fn[s_idx[p + 1] * DIM + t];
            a2 += fn[s_idx[p + 2] * DIM + t];
            a3 += fn[s_idx[p + 3] * DIM + t];
        }
        for (; p < cnt; ++p) a0 += fn[s_idx[p] * DIM + t];
        cs[c * DIM + t] = (a0 + a1) + (a2 + a3);
    }
}

// ---------------- main: fused sim-GEMM + masked neg-max (partials, no atomics) ----------------
// grid (32 i-panels, 16 j-chunks); 512 threads = 8 waves (4 wr x 2 wc), wave tile 64x64.
// Double-buffered B staging via global_load_lds (source-XOR-swizzle, linear LDS dest).
// Each block writes its 256-row partial max to nbp[blockIdx.y][rows] — unconditional,
// every slot written every call (deterministic, no zero-init needed).
__global__ __launch_bounds__(512) void k_main(const u16* __restrict__ fb,
                                              const int* __restrict__ lab,
                                              float* __restrict__ nbp) {
    __shared__ u16 Bt[2][128 * 128];      // 64 KB
    __shared__ float red[2][256];         // 2 KB
    const int t = threadIdx.x;
    const int lane = t & 63, w = t >> 6;
    const int wr = w >> 1, wc = w & 1;    // wr 0..3, wc 0..1
    const int i0 = blockIdx.x * 256;
    const int jbase = blockIdx.y * 512;
    const int l15 = lane & 15, l4 = lane >> 4;

    auto stage = [&](int jt, int buf) {
        const int j0 = jbase + jt * 128;
        #pragma unroll
        for (int it = 0; it < 4; ++it) {
            int q = it * 512 + t;                 // 16B chunk id, 2048 total
            int brow = q >> 4, kb = q & 15;
            load_lds16(fb + (j0 + brow) * DIM + ((kb ^ (brow & 7)) * 8),
                       &Bt[buf][q * 8]);
        }
    };

    // A fragments: row = i0 + wr*64 + m*16 + l15, k = ks*32 + l4*8
    bf16x8 a[4][4];
    #pragma unroll
    for (int m = 0; m < 4; ++m)
        #pragma unroll
        for (int ks = 0; ks < 4; ++ks)
            a[m][ks] = *reinterpret_cast<const bf16x8*>(
                fb + (i0 + wr * 64 + m * 16 + l15) * DIM + ks * 32 + l4 * 8);

    // output-row labels: row = i0 + wr*64 + m*16 + l4*4 + rg
    int labr[4][4];
    #pragma unroll
    for (int m = 0; m < 4; ++m)
        #pragma unroll
        for (int rg = 0; rg < 4; ++rg)
            labr[m][rg] = lab[i0 + wr * 64 + m * 16 + l4 * 4 + rg];

    // column labels for all 4 j-tiles: col = jbase + jt*128 + wc*64 + n*16 + l15
    int labc[4][4];
    #pragma unroll
    for (int jt = 0; jt < 4; ++jt)
        #pragma unroll
        for (int n = 0; n < 4; ++n)
            labc[jt][n] = lab[jbase + jt * 128 + wc * 64 + n * 16 + l15];

    float negp[4][4];
    #pragma unroll
    for (int m = 0; m < 4; ++m)
        #pragma unroll
        for (int rg = 0; rg < 4; ++rg) negp[m][rg] = -1e9f;

    stage(0, 0);
    __syncthreads();

    #pragma unroll
    for (int jt = 0; jt < 4; ++jt) {
        const int cb = jt & 1;
        if (jt < 3) stage(jt + 1, cb ^ 1);   // prefetch next tile under compute

        f32x4 acc[4][4];
        #pragma unroll
        for (int m = 0; m < 4; ++m)
            #pragma unroll
            for (int n = 0; n < 4; ++n) acc[m][n] = f32x4{0.f, 0.f, 0.f, 0.f};

        #pragma unroll
        for (int ks = 0; ks < 4; ++ks) {
            bf16x8 b[4];
            #pragma unroll
            for (int n = 0; n < 4; ++n) {
                int brow = wc * 64 + n * 16 + l15;
                int kb = ks * 4 + l4;
                b[n] = *reinterpret_cast<const bf16x8*>(
                    &Bt[cb][brow * DIM + ((kb ^ (brow & 7)) * 8)]);
            }
            #pragma unroll
            for (int m = 0; m < 4; ++m)
                #pragma unroll
                for (int n = 0; n < 4; ++n)
                    acc[m][n] = __builtin_amdgcn_mfma_f32_16x16x32_bf16(a[m][ks], b[n],
                                                                        acc[m][n], 0, 0, 0);
        }

        // masked neg-max epilogue
        #pragma unroll
        for (int m = 0; m < 4; ++m)
            #pragma unroll
            for (int n = 0; n < 4; ++n) {
                int lc = labc[jt][n];
                #pragma unroll
                for (int rg = 0; rg < 4; ++rg) {
                    float s = acc[m][n][rg];
                    float v = (labr[m][rg] != lc) ? s : -1e9f;
                    negp[m][rg] = fmaxf(negp[m][rg], v);
                }
            }
        __syncthreads();   // drains prefetch + protects Bt[cb]
    }

    // per-row reduce across the 16 lanes (cols) sharing each row
    #pragma unroll
    for (int m = 0; m < 4; ++m)
        #pragma unroll
        for (int rg = 0; rg < 4; ++rg) {
            float v = negp[m][rg];
            v = fmaxf(v, __shfl_xor(v, 1));
            v = fmaxf(v, __shfl_xor(v, 2));
            v = fmaxf(v, __shfl_xor(v, 4));
            v = fmaxf(v, __shfl_xor(v, 8));
            negp[m][rg] = v;
        }
    if (l15 == 0) {
        #pragma unroll
        for (int m = 0; m < 4; ++m)
            #pragma unroll
            for (int rg = 0; rg < 4; ++rg)
                red[wc][wr * 64 + m * 16 + l4 * 4 + rg] = negp[m][rg];
    }
    __syncthreads();
    if (t < 256) {
        float v = fmaxf(red[0][t], red[1][t]);
        nbp[blockIdx.y * N_ROWS + i0 + t] = v;   // unconditional partial write
    }
}

// ---------------- fused posdot + neg-reduce + loss partial (64 blocks) ----------------
__global__ void k_loss(const float* __restrict__ fn, const float* __restrict__ cs,
                       const int* __restrict__ lab, const float* __restrict__ nbp,
                       const int* __restrict__ hist, float* __restrict__ lpart) {
    int t = threadIdx.x, lane = t & 63, w = t >> 6;
    int rbase = blockIdx.x * 128 + w * 32;
    int half = lane >> 5;             // 2 rows per wave-iteration
    int d0 = (lane & 31) * 4;
    float acc = 0.f;
    #pragma unroll
    for (int k = 0; k < 16; ++k) {
        int row = rbase + k * 2 + half;
        int c = lab[row];
        float4 x = *reinterpret_cast<const float4*>(fn + row * DIM + d0);
        float4 y = *reinterpret_cast<const float4*>(cs + c * DIM + d0);
        float s = x.x * y.x + x.y * y.y + x.z * y.z + x.w * y.w;
        s += __shfl_xor(s, 16); s += __shfl_xor(s, 8);
        s += __shfl_xor(s, 4);  s += __shfl_xor(s, 2); s += __shfl_xor(s, 1);
        if ((lane & 31) == 0) {
            float nm = -1e9f;
            #pragma unroll
            for (int jc = 0; jc < 16; ++jc)
                nm = fmaxf(nm, nbp[jc * N_ROWS + row]);
            float neg = nm > -1e8f ? nm : 0.0f;
            int cnt = hist[c] - 1;
            float pos = cnt > 0 ? (s - 1.0f) / (float)cnt : 0.0f;
            acc += fmaxf(0.0f, MARGIN + neg - pos);
        }
    }
    #pragma unroll
    for (int off = 32; off; off >>= 1) acc += __shfl_xor(acc, off);
    __shared__ float sm[4];
    if (lane == 0) sm[w] = acc;
    __syncthreads();
    if (t == 0) lpart[blockIdx.x] = (sm[0] + sm[1]) + (sm[2] + sm[3]);
}

// ---------------- final scalar (sum 64 partials) ----------------
__global__ void k_out(const float* __restrict__ lpart, float* __restrict__ out) {
    int t = threadIdx.x;
    float v = lpart[t];
    #pragma unroll
    for (int off = 32; off; off >>= 1) v += __shfl_xor(v, off);
    if (t == 0) out[0] = v * (1.0f / (float)N_ROWS);
}

extern "C" void kernel_launch(void* const* d_in, const int* in_sizes, int n_in,
                              void* d_out, int out_size, void* d_ws, size_t ws_size,
                              hipStream_t stream) {
    const float* feat = (const float*)d_in[0];
    const int* lab    = (const int*)d_in[1];
    char* ws = (char*)d_ws;
    float*    fn    = (float*)ws;                                  // 4 MB
    u16*      fb    = (u16*)(ws + (4u << 20));                     // 2 MB
    float*    cs    = (float*)(ws + (6u << 20));                   // 256 KB
    float*    nbp   = (float*)(ws + (6u << 20) + (256u << 10));    // 512 KB
    int*      hist  = (int*)(ws + (6u << 20) + (768u << 10));      // 2 KB
    float*    lpart = (float*)(ws + (6u << 20) + (770u << 10));    // 256 B
    float*    out   = (float*)d_out;

    k_prep  <<<2048, 256, 0, stream>>>(feat, fn, fb);
    k_clsum <<<512,  256, 0, stream>>>(lab, fn, cs, hist);
    k_main  <<<dim3(32, 16), 512, 0, stream>>>(fb, lab, nbp);
    k_loss  <<<64,   256, 0, stream>>>(fn, cs, lab, nbp, hist, lpart);
    k_out   <<<1,    64,  0, stream>>>(lpart, out);
}

// Round 5
// 62.027 us; speedup vs baseline: 1.4462x; 1.0404x over previous
//
#include <hip/hip_runtime.h>
#include <hip/hip_bf16.h>

#define N_ROWS 8192
#define DIM    128
#define NCLASS 512
#define MARGIN 0.3f

typedef unsigned short u16;
typedef __attribute__((ext_vector_type(8))) short bf16x8;
typedef __attribute__((ext_vector_type(4))) float f32x4;

__device__ inline void load_lds16(const u16* g, u16* l) {
    __builtin_amdgcn_global_load_lds((const __attribute__((address_space(1))) void*)g,
                                     (__attribute__((address_space(3))) void*)l, 16, 0, 0);
}

// ---------------- normalize rows, emit f32 + bf16 ----------------
__global__ void k_prep(const float* __restrict__ feat, float* __restrict__ fn,
                       u16* __restrict__ fb) {
    int w = threadIdx.x >> 6, lane = threadIdx.x & 63;
    int row = blockIdx.x * 4 + w;
    float2 v = *reinterpret_cast<const float2*>(feat + row * DIM + lane * 2);
    float ss = v.x * v.x + v.y * v.y;
    #pragma unroll
    for (int off = 32; off; off >>= 1) ss += __shfl_xor(ss, off);
    float r = 1.0f / fmaxf(sqrtf(ss), 1e-12f);
    float x = v.x * r, y = v.y * r;
    *reinterpret_cast<float2*>(fn + row * DIM + lane * 2) = make_float2(x, y);
    __hip_bfloat16 bx = __float2bfloat16(x), by = __float2bfloat16(y);
    u16 ux = *reinterpret_cast<u16*>(&bx), uy = *reinterpret_cast<u16*>(&by);
    ushort2 p; p.x = ux; p.y = uy;
    *reinterpret_cast<ushort2*>(fb + row * DIM + lane * 2) = p;
}

// ---------------- class sums S_c + per-class histogram ----------------
__global__ void k_clsum(const int* __restrict__ lab, const float* __restrict__ fn,
                        float* __restrict__ cs, int* __restrict__ hist) {
    __shared__ int s_cnt;
    __shared__ int s_idx[128];
    int t = threadIdx.x, c = blockIdx.x;
    if (t == 0) s_cnt = 0;
    __syncthreads();
    for (int q = t; q < N_ROWS / 4; q += 256) {
        int4 L = reinterpret_cast<const int4*>(lab)[q];
        if (L.x == c) { int p = atomicAdd(&s_cnt, 1); if (p < 128) s_idx[p] = q * 4 + 0; }
        if (L.y == c) { int p = atomicAdd(&s_cnt, 1); if (p < 128) s_idx[p] = q * 4 + 1; }
        if (L.z == c) { int p = atomicAdd(&s_cnt, 1); if (p < 128) s_idx[p] = q * 4 + 2; }
        if (L.w == c) { int p = atomicAdd(&s_cnt, 1); if (p < 128) s_idx[p] = q * 4 + 3; }
    }
    __syncthreads();
    if (t == 0) hist[c] = s_cnt;
    int cnt = s_cnt < 128 ? s_cnt : 128;
    if (t < DIM) {
        float a0 = 0.f, a1 = 0.f, a2 = 0.f, a3 = 0.f;
        int p = 0;
        for (; p + 4 <= cnt; p += 4) {
            a0 += fn[s_idx[p + 0] * DIM + t];
            a1 += fn[s_idx[p + 1] * DIM + t];
            a2 += fn[s_idx[p + 2] * DIM + t];
            a3 += fn[s_idx[p + 3] * DIM + t];
        }
        for (; p < cnt; ++p) a0 += fn[s_idx[p] * DIM + t];
        cs[c * DIM + t] = (a0 + a1) + (a2 + a3);
    }
}

// ---------------- main: fused sim-GEMM + masked neg-max ----------------
// Wave tile 32x64 (a 32 + acc 32 VGPR -> fits 4 waves/SIMD). 512 thr = 8 waves
// (4 wr x 2 wc), block tile 128 rows x 512 cols, grid (64,16) = 1024 blocks =
// 2 blocks/CU (LDS 65KB). Double-buffered B staging via global_load_lds
// (source-XOR-swizzle, linear LDS dest). Partial-max writes, no atomics.
__global__ __launch_bounds__(512, 4) void k_main(const u16* __restrict__ fb,
                                                 const int* __restrict__ lab,
                                                 float* __restrict__ nbp) {
    __shared__ u16 Bt[2][128 * 128];      // 64 KB
    __shared__ float red[2][128];         // 1 KB
    const int t = threadIdx.x;
    const int lane = t & 63, w = t >> 6;
    const int wr = w >> 1, wc = w & 1;    // wr 0..3 (32-row strips), wc 0..1 (64-col strips)
    const int i0 = blockIdx.x * 128;
    const int jbase = blockIdx.y * 512;
    const int l15 = lane & 15, l4 = lane >> 4;

    auto stage = [&](int jt, int buf) {
        const int j0 = jbase + jt * 128;
        #pragma unroll
        for (int it = 0; it < 4; ++it) {
            int q = it * 512 + t;                 // 16B chunk id, 2048 total
            int brow = q >> 4, kb = q & 15;
            load_lds16(fb + (j0 + brow) * DIM + ((kb ^ (brow & 7)) * 8),
                       &Bt[buf][q * 8]);
        }
    };

    // A fragments: row = i0 + wr*32 + m*16 + l15, k = ks*32 + l4*8   (32 VGPR)
    bf16x8 a[2][4];
    #pragma unroll
    for (int m = 0; m < 2; ++m)
        #pragma unroll
        for (int ks = 0; ks < 4; ++ks)
            a[m][ks] = *reinterpret_cast<const bf16x8*>(
                fb + (i0 + wr * 32 + m * 16 + l15) * DIM + ks * 32 + l4 * 8);

    // output-row labels: row = i0 + wr*32 + m*16 + l4*4 + rg
    int labr[2][4];
    #pragma unroll
    for (int m = 0; m < 2; ++m)
        #pragma unroll
        for (int rg = 0; rg < 4; ++rg)
            labr[m][rg] = lab[i0 + wr * 32 + m * 16 + l4 * 4 + rg];

    float negp[2][4];
    #pragma unroll
    for (int m = 0; m < 2; ++m)
        #pragma unroll
        for (int rg = 0; rg < 4; ++rg) negp[m][rg] = -1e9f;

    stage(0, 0);
    __syncthreads();

    #pragma unroll
    for (int jt = 0; jt < 4; ++jt) {
        const int cb = jt & 1;
        if (jt < 3) stage(jt + 1, cb ^ 1);   // prefetch next tile under compute

        // column labels: col = j0 + wc*64 + n*16 + l15
        const int j0 = jbase + jt * 128;
        int labc[4];
        #pragma unroll
        for (int n = 0; n < 4; ++n) labc[n] = lab[j0 + wc * 64 + n * 16 + l15];

        f32x4 acc[2][4];
        #pragma unroll
        for (int m = 0; m < 2; ++m)
            #pragma unroll
            for (int n = 0; n < 4; ++n) acc[m][n] = f32x4{0.f, 0.f, 0.f, 0.f};

        __builtin_amdgcn_s_setprio(1);
        #pragma unroll
        for (int ks = 0; ks < 4; ++ks) {
            bf16x8 b[4];
            #pragma unroll
            for (int n = 0; n < 4; ++n) {
                int brow = wc * 64 + n * 16 + l15;
                int kb = ks * 4 + l4;
                b[n] = *reinterpret_cast<const bf16x8*>(
                    &Bt[cb][brow * DIM + ((kb ^ (brow & 7)) * 8)]);
            }
            #pragma unroll
            for (int m = 0; m < 2; ++m)
                #pragma unroll
                for (int n = 0; n < 4; ++n)
                    acc[m][n] = __builtin_amdgcn_mfma_f32_16x16x32_bf16(a[m][ks], b[n],
                                                                        acc[m][n], 0, 0, 0);
        }
        __builtin_amdgcn_s_setprio(0);

        // masked neg-max epilogue
        #pragma unroll
        for (int m = 0; m < 2; ++m)
            #pragma unroll
            for (int n = 0; n < 4; ++n) {
                int lc = labc[n];
                #pragma unroll
                for (int rg = 0; rg < 4; ++rg) {
                    float s = acc[m][n][rg];
                    float v = (labr[m][rg] != lc) ? s : -1e9f;
                    negp[m][rg] = fmaxf(negp[m][rg], v);
                }
            }
        __syncthreads();   // drains prefetch + protects Bt[cb]
    }

    // per-row reduce across the 16 lanes (cols) sharing each row
    #pragma unroll
    for (int m = 0; m < 2; ++m)
        #pragma unroll
        for (int rg = 0; rg < 4; ++rg) {
            float v = negp[m][rg];
            v = fmaxf(v, __shfl_xor(v, 1));
            v = fmaxf(v, __shfl_xor(v, 2));
            v = fmaxf(v, __shfl_xor(v, 4));
            v = fmaxf(v, __shfl_xor(v, 8));
            negp[m][rg] = v;
        }
    if (l15 == 0) {
        #pragma unroll
        for (int m = 0; m < 2; ++m)
            #pragma unroll
            for (int rg = 0; rg < 4; ++rg)
                red[wc][wr * 32 + m * 16 + l4 * 4 + rg] = negp[m][rg];
    }
    __syncthreads();
    if (t < 128) {
        float v = fmaxf(red[0][t], red[1][t]);
        nbp[blockIdx.y * N_ROWS + i0 + t] = v;   // unconditional partial write
    }
}

// ---------------- fused posdot + neg-reduce + loss partial (64 blocks) ----------------
__global__ void k_loss(const float* __restrict__ fn, const float* __restrict__ cs,
                       const int* __restrict__ lab, const float* __restrict__ nbp,
                       const int* __restrict__ hist, float* __restrict__ lpart) {
    int t = threadIdx.x, lane = t & 63, w = t >> 6;
    int rbase = blockIdx.x * 128 + w * 32;
    int half = lane >> 5;             // 2 rows per wave-iteration
    int d0 = (lane & 31) * 4;
    float acc = 0.f;
    #pragma unroll
    for (int k = 0; k < 16; ++k) {
        int row = rbase + k * 2 + half;
        int c = lab[row];
        float4 x = *reinterpret_cast<const float4*>(fn + row * DIM + d0);
        float4 y = *reinterpret_cast<const float4*>(cs + c * DIM + d0);
        float s = x.x * y.x + x.y * y.y + x.z * y.z + x.w * y.w;
        s += __shfl_xor(s, 16); s += __shfl_xor(s, 8);
        s += __shfl_xor(s, 4);  s += __shfl_xor(s, 2); s += __shfl_xor(s, 1);
        if ((lane & 31) == 0) {
            float nm = -1e9f;
            #pragma unroll
            for (int jc = 0; jc < 16; ++jc)
                nm = fmaxf(nm, nbp[jc * N_ROWS + row]);
            float neg = nm > -1e8f ? nm : 0.0f;
            int cnt = hist[c] - 1;
            float pos = cnt > 0 ? (s - 1.0f) / (float)cnt : 0.0f;
            acc += fmaxf(0.0f, MARGIN + neg - pos);
        }
    }
    #pragma unroll
    for (int off = 32; off; off >>= 1) acc += __shfl_xor(acc, off);
    __shared__ float sm[4];
    if (lane == 0) sm[w] = acc;
    __syncthreads();
    if (t == 0) lpart[blockIdx.x] = (sm[0] + sm[1]) + (sm[2] + sm[3]);
}

// ---------------- final scalar (sum 64 partials) ----------------
__global__ void k_out(const float* __restrict__ lpart, float* __restrict__ out) {
    int t = threadIdx.x;
    float v = lpart[t];
    #pragma unroll
    for (int off = 32; off; off >>= 1) v += __shfl_xor(v, off);
    if (t == 0) out[0] = v * (1.0f / (float)N_ROWS);
}

extern "C" void kernel_launch(void* const* d_in, const int* in_sizes, int n_in,
                              void* d_out, int out_size, void* d_ws, size_t ws_size,
                              hipStream_t stream) {
    const float* feat = (const float*)d_in[0];
    const int* lab    = (const int*)d_in[1];
    char* ws = (char*)d_ws;
    float*    fn    = (float*)ws;                                  // 4 MB
    u16*      fb    = (u16*)(ws + (4u << 20));                     // 2 MB
    float*    cs    = (float*)(ws + (6u << 20));                   // 256 KB
    float*    nbp   = (float*)(ws + (6u << 20) + (256u << 10));    // 512 KB
    int*      hist  = (int*)(ws + (6u << 20) + (768u << 10));      // 2 KB
    float*    lpart = (float*)(ws + (6u << 20) + (770u << 10));    // 256 B
    float*    out   = (float*)d_out;

    k_prep  <<<2048, 256, 0, stream>>>(feat, fn, fb);
    k_clsum <<<512,  256, 0, stream>>>(lab, fn, cs, hist);
    k_main  <<<dim3(64, 16), 512, 0, stream>>>(fb, lab, nbp);
    k_loss  <<<64,   256, 0, stream>>>(fn, cs, lab, nbp, hist, lpart);
    k_out   <<<1,    64,  0, stream>>>(lpart, out);
}

// Round 6
// 58.635 us; speedup vs baseline: 1.5298x; 1.0578x over previous
//
#include <hip/hip_runtime.h>
#include <hip/hip_bf16.h>

#define N_ROWS 8192
#define DIM    128
#define NCLASS 512
#define MARGIN 0.3f

typedef unsigned short u16;
typedef __attribute__((ext_vector_type(8))) short bf16x8;
typedef __attribute__((ext_vector_type(4))) float f32x4;

__device__ inline void load_lds16(const u16* g, u16* l) {
    __builtin_amdgcn_global_load_lds((const __attribute__((address_space(1))) void*)g,
                                     (__attribute__((address_space(3))) void*)l, 16, 0, 0);
}

// ---------------- normalize rows, emit f32 + bf16 ----------------
__global__ void k_prep(const float* __restrict__ feat, float* __restrict__ fn,
                       u16* __restrict__ fb) {
    int w = threadIdx.x >> 6, lane = threadIdx.x & 63;
    int row = blockIdx.x * 4 + w;
    float2 v = *reinterpret_cast<const float2*>(feat + row * DIM + lane * 2);
    float ss = v.x * v.x + v.y * v.y;
    #pragma unroll
    for (int off = 32; off; off >>= 1) ss += __shfl_xor(ss, off);
    float r = 1.0f / fmaxf(sqrtf(ss), 1e-12f);
    float x = v.x * r, y = v.y * r;
    *reinterpret_cast<float2*>(fn + row * DIM + lane * 2) = make_float2(x, y);
    __hip_bfloat16 bx = __float2bfloat16(x), by = __float2bfloat16(y);
    u16 ux = *reinterpret_cast<u16*>(&bx), uy = *reinterpret_cast<u16*>(&by);
    ushort2 p; p.x = ux; p.y = uy;
    *reinterpret_cast<ushort2*>(fb + row * DIM + lane * 2) = p;
}

// ---------------- class sums S_c + per-class histogram ----------------
__global__ void k_clsum(const int* __restrict__ lab, const float* __restrict__ fn,
                        float* __restrict__ cs, int* __restrict__ hist) {
    __shared__ int s_cnt;
    __shared__ int s_idx[128];
    int t = threadIdx.x, c = blockIdx.x;
    if (t == 0) s_cnt = 0;
    __syncthreads();
    for (int q = t; q < N_ROWS / 4; q += 256) {
        int4 L = reinterpret_cast<const int4*>(lab)[q];
        if (L.x == c) { int p = atomicAdd(&s_cnt, 1); if (p < 128) s_idx[p] = q * 4 + 0; }
        if (L.y == c) { int p = atomicAdd(&s_cnt, 1); if (p < 128) s_idx[p] = q * 4 + 1; }
        if (L.z == c) { int p = atomicAdd(&s_cnt, 1); if (p < 128) s_idx[p] = q * 4 + 2; }
        if (L.w == c) { int p = atomicAdd(&s_cnt, 1); if (p < 128) s_idx[p] = q * 4 + 3; }
    }
    __syncthreads();
    if (t == 0) hist[c] = s_cnt;
    int cnt = s_cnt < 128 ? s_cnt : 128;
    if (t < DIM) {
        float a0 = 0.f, a1 = 0.f, a2 = 0.f, a3 = 0.f;
        int p = 0;
        for (; p + 4 <= cnt; p += 4) {
            a0 += fn[s_idx[p + 0] * DIM + t];
            a1 += fn[s_idx[p + 1] * DIM + t];
            a2 += fn[s_idx[p + 2] * DIM + t];
            a3 += fn[s_idx[p + 3] * DIM + t];
        }
        for (; p < cnt; ++p) a0 += fn[s_idx[p] * DIM + t];
        cs[c * DIM + t] = (a0 + a1) + (a2 + a3);
    }
}

// ---------------- main: symmetric fused sim-GEMM + masked neg-max ----------------
// Upper-triangle tiles only: 2080 blocks, each computes one 128x128 tile (bi<=bj)
// and emits BOTH row-direction (panel bi) and col-direction (panel bj) masked
// maxes (sim and the label mask are symmetric). 512 thr = 8 waves (4 wr x 2 wc),
// wave tile 32x64. B staged once via global_load_lds (source-XOR-swizzle, linear
// LDS dest). nbp[row][64]: slot bj from row path, slot bi from col path; diagonal
// block writes row path only => every slot written exactly once, no atomics.
__global__ __launch_bounds__(512, 4) void k_main(const u16* __restrict__ fb,
                                                 const int* __restrict__ lab,
                                                 float* __restrict__ nbp) {
    __shared__ u16 Bt[128 * 128];         // 32 KB
    __shared__ float redr[2][128];        // row partials by wc
    __shared__ float redc[4][128];        // col partials by wr
    const int t = threadIdx.x;
    const int lane = t & 63, w = t >> 6;
    const int wr = w >> 1, wc = w & 1;    // wr 0..3 (32-row strips), wc 0..1 (64-col strips)
    const int l15 = lane & 15, l4 = lane >> 4;

    // invert linear block id -> (bi, bj) upper triangle, bi<=bj, 64x64 panels
    int tt = blockIdx.x;
    int bi = (int)((129.0f - sqrtf(16641.0f - 8.0f * (float)tt)) * 0.5f);
    while (bi * 64 - bi * (bi - 1) / 2 > tt) --bi;
    while ((bi + 1) * 64 - (bi + 1) * bi / 2 <= tt) ++bi;
    const int bj = bi + (tt - (bi * 64 - bi * (bi - 1) / 2));
    const int i0 = bi * 128, j0 = bj * 128;

    // stage B tile = fb rows j0..j0+127 (2048 x 16B chunks, 4 per thread)
    #pragma unroll
    for (int it = 0; it < 4; ++it) {
        int q = it * 512 + t;
        int brow = q >> 4, kb = q & 15;
        load_lds16(fb + (j0 + brow) * DIM + ((kb ^ (brow & 7)) * 8), Bt + q * 8);
    }

    // A fragments: row = i0 + wr*32 + m*16 + l15, k = ks*32 + l4*8
    bf16x8 a[2][4];
    #pragma unroll
    for (int m = 0; m < 2; ++m)
        #pragma unroll
        for (int ks = 0; ks < 4; ++ks)
            a[m][ks] = *reinterpret_cast<const bf16x8*>(
                fb + (i0 + wr * 32 + m * 16 + l15) * DIM + ks * 32 + l4 * 8);

    // output-row labels: row = i0 + wr*32 + m*16 + l4*4 + rg
    int labr[2][4];
    #pragma unroll
    for (int m = 0; m < 2; ++m)
        #pragma unroll
        for (int rg = 0; rg < 4; ++rg)
            labr[m][rg] = lab[i0 + wr * 32 + m * 16 + l4 * 4 + rg];

    // column labels: col = j0 + wc*64 + n*16 + l15
    int labc[4];
    #pragma unroll
    for (int n = 0; n < 4; ++n) labc[n] = lab[j0 + wc * 64 + n * 16 + l15];

    __syncthreads();   // compiler drains vmcnt before barrier -> Bt ready

    f32x4 acc[2][4];
    #pragma unroll
    for (int m = 0; m < 2; ++m)
        #pragma unroll
        for (int n = 0; n < 4; ++n) acc[m][n] = f32x4{0.f, 0.f, 0.f, 0.f};

    __builtin_amdgcn_s_setprio(1);
    #pragma unroll
    for (int ks = 0; ks < 4; ++ks) {
        bf16x8 b[4];
        #pragma unroll
        for (int n = 0; n < 4; ++n) {
            int brow = wc * 64 + n * 16 + l15;
            int kb = ks * 4 + l4;
            b[n] = *reinterpret_cast<const bf16x8*>(
                Bt + brow * DIM + ((kb ^ (brow & 7)) * 8));
        }
        #pragma unroll
        for (int m = 0; m < 2; ++m)
            #pragma unroll
            for (int n = 0; n < 4; ++n)
                acc[m][n] = __builtin_amdgcn_mfma_f32_16x16x32_bf16(a[m][ks], b[n],
                                                                    acc[m][n], 0, 0, 0);
    }
    __builtin_amdgcn_s_setprio(0);

    // masked epilogue: v computed once, feeds row-max AND col-max
    float negp[2][4];
    float colv[4];
    #pragma unroll
    for (int m = 0; m < 2; ++m)
        #pragma unroll
        for (int rg = 0; rg < 4; ++rg) negp[m][rg] = -1e9f;
    #pragma unroll
    for (int n = 0; n < 4; ++n) colv[n] = -1e9f;

    #pragma unroll
    for (int m = 0; m < 2; ++m)
        #pragma unroll
        for (int n = 0; n < 4; ++n) {
            int lc = labc[n];
            #pragma unroll
            for (int rg = 0; rg < 4; ++rg) {
                float s = acc[m][n][rg];
                float v = (labr[m][rg] != lc) ? s : -1e9f;
                negp[m][rg] = fmaxf(negp[m][rg], v);
                colv[n] = fmaxf(colv[n], v);
            }
        }

    // row reduce across the 16 lanes (cols) sharing each row
    #pragma unroll
    for (int m = 0; m < 2; ++m)
        #pragma unroll
        for (int rg = 0; rg < 4; ++rg) {
            float v = negp[m][rg];
            v = fmaxf(v, __shfl_xor(v, 1));
            v = fmaxf(v, __shfl_xor(v, 2));
            v = fmaxf(v, __shfl_xor(v, 4));
            v = fmaxf(v, __shfl_xor(v, 8));
            negp[m][rg] = v;
        }
    if (l15 == 0) {
        #pragma unroll
        for (int m = 0; m < 2; ++m)
            #pragma unroll
            for (int rg = 0; rg < 4; ++rg)
                redr[wc][wr * 32 + m * 16 + l4 * 4 + rg] = negp[m][rg];
    }

    // col reduce across the 4 l4 groups (rows) sharing each col
    #pragma unroll
    for (int n = 0; n < 4; ++n) {
        float v = colv[n];
        v = fmaxf(v, __shfl_xor(v, 16));
        v = fmaxf(v, __shfl_xor(v, 32));
        colv[n] = v;
    }
    if (l4 == 0) {
        #pragma unroll
        for (int n = 0; n < 4; ++n)
            redc[wr][wc * 64 + n * 16 + l15] = colv[n];
    }
    __syncthreads();

    if (t < 128) {
        float rv = fmaxf(redr[0][t], redr[1][t]);
        nbp[(i0 + t) * 64 + bj] = rv;                      // row-path slot, exactly once
        if (bi != bj) {
            float cv = fmaxf(fmaxf(redc[0][t], redc[1][t]),
                             fmaxf(redc[2][t], redc[3][t]));
            nbp[(j0 + t) * 64 + bi] = cv;                  // col-path slot, exactly once
        }
    }
}

// ---------------- fused posdot + neg-reduce + loss partial ----------------
// 256 blocks x 4 waves, one row per wave-iteration: lane = nbp slot (64 slots),
// float2 per-lane dot, single shfl chain carries sum and max together.
__global__ void k_loss(const float* __restrict__ fn, const float* __restrict__ cs,
                       const int* __restrict__ lab, const float* __restrict__ nbp,
                       const int* __restrict__ hist, float* __restrict__ lpart) {
    int t = threadIdx.x, lane = t & 63, w = t >> 6;
    int rbase = blockIdx.x * 32 + w * 8;
    float acc = 0.f;
    #pragma unroll
    for (int k = 0; k < 8; ++k) {
        int row = rbase + k;
        int c = lab[row];
        float2 x = *reinterpret_cast<const float2*>(fn + row * DIM + lane * 2);
        float2 y = *reinterpret_cast<const float2*>(cs + c * DIM + lane * 2);
        float s = x.x * y.x + x.y * y.y;
        float nm = nbp[row * 64 + lane];
        #pragma unroll
        for (int off = 32; off; off >>= 1) {
            s += __shfl_xor(s, off);
            nm = fmaxf(nm, __shfl_xor(nm, off));
        }
        if (lane == 0) {
            float neg = nm > -1e8f ? nm : 0.0f;
            int cnt = hist[c] - 1;
            float pos = cnt > 0 ? (s - 1.0f) / (float)cnt : 0.0f;
            acc += fmaxf(0.0f, MARGIN + neg - pos);
        }
    }
    __shared__ float sm[4];
    if (lane == 0) sm[w] = acc;
    __syncthreads();
    if (t == 0) lpart[blockIdx.x] = (sm[0] + sm[1]) + (sm[2] + sm[3]);
}

// ---------------- final scalar (sum 256 partials) ----------------
__global__ void k_out(const float* __restrict__ lpart, float* __restrict__ out) {
    int t = threadIdx.x;
    float v = lpart[t] + lpart[t + 64] + lpart[t + 128] + lpart[t + 192];
    #pragma unroll
    for (int off = 32; off; off >>= 1) v += __shfl_xor(v, off);
    if (t == 0) out[0] = v * (1.0f / (float)N_ROWS);
}

extern "C" void kernel_launch(void* const* d_in, const int* in_sizes, int n_in,
                              void* d_out, int out_size, void* d_ws, size_t ws_size,
                              hipStream_t stream) {
    const float* feat = (const float*)d_in[0];
    const int* lab    = (const int*)d_in[1];
    char* ws = (char*)d_ws;
    float*    fn    = (float*)ws;                                  // 4 MB
    u16*      fb    = (u16*)(ws + (4u << 20));                     // 2 MB
    float*    cs    = (float*)(ws + (6u << 20));                   // 256 KB
    float*    nbp   = (float*)(ws + (6u << 20) + (256u << 10));    // 2 MB [8192][64]
    int*      hist  = (int*)(ws + (6u << 20) + (2304u << 10));     // 2 KB
    float*    lpart = (float*)(ws + (6u << 20) + (2306u << 10));   // 1 KB
    float*    out   = (float*)d_out;

    k_prep  <<<2048, 256, 0, stream>>>(feat, fn, fb);
    k_clsum <<<512,  256, 0, stream>>>(lab, fn, cs, hist);
    k_main  <<<2080, 512, 0, stream>>>(fb, lab, nbp);
    k_loss  <<<256,  256, 0, stream>>>(fn, cs, lab, nbp, hist, lpart);
    k_out   <<<1,    64,  0, stream>>>(lpart, out);
}

// Round 7
// 55.154 us; speedup vs baseline: 1.6264x; 1.0631x over previous
//
#include <hip/hip_runtime.h>
#include <hip/hip_bf16.h>

#define N_ROWS 8192
#define DIM    128
#define NCLASS 512
#define MARGIN 0.3f

typedef unsigned short u16;
typedef __attribute__((ext_vector_type(8))) short bf16x8;
typedef __attribute__((ext_vector_type(4))) float f32x4;

__device__ inline void load_lds16(const u16* g, u16* l) {
    __builtin_amdgcn_global_load_lds((const __attribute__((address_space(1))) void*)g,
                                     (__attribute__((address_space(3))) void*)l, 16, 0, 0);
}

// ---------------- fused prep: normalize->fb (blocks 0..2047)  ||  class sums (blocks 2048..2559) ----------------
__global__ void k_prep2(const float* __restrict__ feat, const int* __restrict__ lab,
                        u16* __restrict__ fb, float* __restrict__ cs, int* __restrict__ hist) {
    const int t = threadIdx.x, lane = t & 63, w = t >> 6;
    if (blockIdx.x < 2048) {
        // role A: normalize 4 rows -> bf16 fb
        int row = blockIdx.x * 4 + w;
        float2 v = *reinterpret_cast<const float2*>(feat + row * DIM + lane * 2);
        float ss = v.x * v.x + v.y * v.y;
        #pragma unroll
        for (int off = 32; off; off >>= 1) ss += __shfl_xor(ss, off);
        float r = 1.0f / fmaxf(sqrtf(ss), 1e-12f);
        float x = v.x * r, y = v.y * r;
        __hip_bfloat16 bx = __float2bfloat16(x), by = __float2bfloat16(y);
        u16 ux = *reinterpret_cast<u16*>(&bx), uy = *reinterpret_cast<u16*>(&by);
        ushort2 p; p.x = ux; p.y = uy;
        *reinterpret_cast<ushort2*>(fb + row * DIM + lane * 2) = p;
        return;
    }
    // role B: class sum for c (gathers RAW rows, renormalizes in-register)
    __shared__ int s_cnt;
    __shared__ int s_idx[128];
    __shared__ float2 part[4][64];
    const int c = blockIdx.x - 2048;
    if (t == 0) s_cnt = 0;
    __syncthreads();
    for (int q = t; q < N_ROWS / 4; q += 256) {
        int4 L = reinterpret_cast<const int4*>(lab)[q];
        if (L.x == c) { int p = atomicAdd(&s_cnt, 1); if (p < 128) s_idx[p] = q * 4 + 0; }
        if (L.y == c) { int p = atomicAdd(&s_cnt, 1); if (p < 128) s_idx[p] = q * 4 + 1; }
        if (L.z == c) { int p = atomicAdd(&s_cnt, 1); if (p < 128) s_idx[p] = q * 4 + 2; }
        if (L.w == c) { int p = atomicAdd(&s_cnt, 1); if (p < 128) s_idx[p] = q * 4 + 3; }
    }
    __syncthreads();
    int cnt = s_cnt < 128 ? s_cnt : 128;
    float sA = 0.f, sB = 0.f;          // lane owns dims 2*lane, 2*lane+1
    for (int p = w; p < cnt; p += 4) { // waves split the class rows
        int r = s_idx[p];
        float2 v = *reinterpret_cast<const float2*>(feat + r * DIM + lane * 2);
        float ss = v.x * v.x + v.y * v.y;
        #pragma unroll
        for (int off = 32; off; off >>= 1) ss += __shfl_xor(ss, off);
        float rr = 1.0f / fmaxf(sqrtf(ss), 1e-12f);
        sA += v.x * rr; sB += v.y * rr;
    }
    part[w][lane] = make_float2(sA, sB);
    __syncthreads();
    if (t < 64) {
        float2 p0 = part[0][t], p1 = part[1][t], p2 = part[2][t], p3 = part[3][t];
        float2 o = make_float2((p0.x + p1.x) + (p2.x + p3.x),
                               (p0.y + p1.y) + (p2.y + p3.y));
        *reinterpret_cast<float2*>(cs + c * DIM + t * 2) = o;
    }
    if (t == 0) hist[c] = s_cnt;
}

// ---------------- main: symmetric fused sim-GEMM + masked neg-max ----------------
// Upper-triangle tiles only: 2080 blocks, each computes one 128x128 tile (bi<=bj)
// and emits BOTH row-direction (panel bi) and col-direction (panel bj) masked
// maxes (sim and the label mask are symmetric). 512 thr = 8 waves (4 wr x 2 wc),
// wave tile 32x64. B staged once via global_load_lds (source-XOR-swizzle, linear
// LDS dest). nbp[row][64]: slot bj from row path, slot bi from col path; diagonal
// block writes row path only => every slot written exactly once, no atomics.
__global__ __launch_bounds__(512, 4) void k_main(const u16* __restrict__ fb,
                                                 const int* __restrict__ lab,
                                                 float* __restrict__ nbp) {
    __shared__ u16 Bt[128 * 128];         // 32 KB
    __shared__ float redr[2][128];        // row partials by wc
    __shared__ float redc[4][128];        // col partials by wr
    const int t = threadIdx.x;
    const int lane = t & 63, w = t >> 6;
    const int wr = w >> 1, wc = w & 1;    // wr 0..3 (32-row strips), wc 0..1 (64-col strips)
    const int l15 = lane & 15, l4 = lane >> 4;

    // invert linear block id -> (bi, bj) upper triangle, bi<=bj, 64x64 panels
    int tt = blockIdx.x;
    int bi = (int)((129.0f - sqrtf(16641.0f - 8.0f * (float)tt)) * 0.5f);
    while (bi * 64 - bi * (bi - 1) / 2 > tt) --bi;
    while ((bi + 1) * 64 - (bi + 1) * bi / 2 <= tt) ++bi;
    const int bj = bi + (tt - (bi * 64 - bi * (bi - 1) / 2));
    const int i0 = bi * 128, j0 = bj * 128;

    // stage B tile = fb rows j0..j0+127 (2048 x 16B chunks, 4 per thread)
    #pragma unroll
    for (int it = 0; it < 4; ++it) {
        int q = it * 512 + t;
        int brow = q >> 4, kb = q & 15;
        load_lds16(fb + (j0 + brow) * DIM + ((kb ^ (brow & 7)) * 8), Bt + q * 8);
    }

    // A fragments: row = i0 + wr*32 + m*16 + l15, k = ks*32 + l4*8
    bf16x8 a[2][4];
    #pragma unroll
    for (int m = 0; m < 2; ++m)
        #pragma unroll
        for (int ks = 0; ks < 4; ++ks)
            a[m][ks] = *reinterpret_cast<const bf16x8*>(
                fb + (i0 + wr * 32 + m * 16 + l15) * DIM + ks * 32 + l4 * 8);

    // output-row labels: row = i0 + wr*32 + m*16 + l4*4 + rg
    int labr[2][4];
    #pragma unroll
    for (int m = 0; m < 2; ++m)
        #pragma unroll
        for (int rg = 0; rg < 4; ++rg)
            labr[m][rg] = lab[i0 + wr * 32 + m * 16 + l4 * 4 + rg];

    // column labels: col = j0 + wc*64 + n*16 + l15
    int labc[4];
    #pragma unroll
    for (int n = 0; n < 4; ++n) labc[n] = lab[j0 + wc * 64 + n * 16 + l15];

    __syncthreads();   // compiler drains vmcnt before barrier -> Bt ready

    f32x4 acc[2][4];
    #pragma unroll
    for (int m = 0; m < 2; ++m)
        #pragma unroll
        for (int n = 0; n < 4; ++n) acc[m][n] = f32x4{0.f, 0.f, 0.f, 0.f};

    __builtin_amdgcn_s_setprio(1);
    #pragma unroll
    for (int ks = 0; ks < 4; ++ks) {
        bf16x8 b[4];
        #pragma unroll
        for (int n = 0; n < 4; ++n) {
            int brow = wc * 64 + n * 16 + l15;
            int kb = ks * 4 + l4;
            b[n] = *reinterpret_cast<const bf16x8*>(
                Bt + brow * DIM + ((kb ^ (brow & 7)) * 8));
        }
        #pragma unroll
        for (int m = 0; m < 2; ++m)
            #pragma unroll
            for (int n = 0; n < 4; ++n)
                acc[m][n] = __builtin_amdgcn_mfma_f32_16x16x32_bf16(a[m][ks], b[n],
                                                                    acc[m][n], 0, 0, 0);
    }
    __builtin_amdgcn_s_setprio(0);

    // masked epilogue: v computed once, feeds row-max AND col-max
    float negp[2][4];
    float colv[4];
    #pragma unroll
    for (int m = 0; m < 2; ++m)
        #pragma unroll
        for (int rg = 0; rg < 4; ++rg) negp[m][rg] = -1e9f;
    #pragma unroll
    for (int n = 0; n < 4; ++n) colv[n] = -1e9f;

    #pragma unroll
    for (int m = 0; m < 2; ++m)
        #pragma unroll
        for (int n = 0; n < 4; ++n) {
            int lc = labc[n];
            #pragma unroll
            for (int rg = 0; rg < 4; ++rg) {
                float s = acc[m][n][rg];
                float v = (labr[m][rg] != lc) ? s : -1e9f;
                negp[m][rg] = fmaxf(negp[m][rg], v);
                colv[n] = fmaxf(colv[n], v);
            }
        }

    // row reduce across the 16 lanes (cols) sharing each row
    #pragma unroll
    for (int m = 0; m < 2; ++m)
        #pragma unroll
        for (int rg = 0; rg < 4; ++rg) {
            float v = negp[m][rg];
            v = fmaxf(v, __shfl_xor(v, 1));
            v = fmaxf(v, __shfl_xor(v, 2));
            v = fmaxf(v, __shfl_xor(v, 4));
            v = fmaxf(v, __shfl_xor(v, 8));
            negp[m][rg] = v;
        }
    if (l15 == 0) {
        #pragma unroll
        for (int m = 0; m < 2; ++m)
            #pragma unroll
            for (int rg = 0; rg < 4; ++rg)
                redr[wc][wr * 32 + m * 16 + l4 * 4 + rg] = negp[m][rg];
    }

    // col reduce across the 4 l4 groups (rows) sharing each col
    #pragma unroll
    for (int n = 0; n < 4; ++n) {
        float v = colv[n];
        v = fmaxf(v, __shfl_xor(v, 16));
        v = fmaxf(v, __shfl_xor(v, 32));
        colv[n] = v;
    }
    if (l4 == 0) {
        #pragma unroll
        for (int n = 0; n < 4; ++n)
            redc[wr][wc * 64 + n * 16 + l15] = colv[n];
    }
    __syncthreads();

    if (t < 128) {
        float rv = fmaxf(redr[0][t], redr[1][t]);
        nbp[(i0 + t) * 64 + bj] = rv;                      // row-path slot, exactly once
        if (bi != bj) {
            float cv = fmaxf(fmaxf(redc[0][t], redc[1][t]),
                             fmaxf(redc[2][t], redc[3][t]));
            nbp[(j0 + t) * 64 + bi] = cv;                  // col-path slot, exactly once
        }
    }
}

// ---------------- fused posdot + neg-reduce + loss partial ----------------
// 256 blocks x 4 waves, one row per wave-iteration: lane = nbp slot (64 slots),
// bf16 per-lane dot (exact bit-shift expand), single shfl chain sum+max.
__global__ void k_loss(const u16* __restrict__ fb, const float* __restrict__ cs,
                       const int* __restrict__ lab, const float* __restrict__ nbp,
                       const int* __restrict__ hist, float* __restrict__ lpart) {
    int t = threadIdx.x, lane = t & 63, w = t >> 6;
    int rbase = blockIdx.x * 32 + w * 8;
    float acc = 0.f;
    #pragma unroll
    for (int k = 0; k < 8; ++k) {
        int row = rbase + k;
        int c = lab[row];
        ushort2 xb = *reinterpret_cast<const ushort2*>(fb + row * DIM + lane * 2);
        float x0 = __uint_as_float((unsigned)xb.x << 16);
        float x1 = __uint_as_float((unsigned)xb.y << 16);
        float2 y = *reinterpret_cast<const float2*>(cs + c * DIM + lane * 2);
        float s = x0 * y.x + x1 * y.y;
        float nm = nbp[row * 64 + lane];
        #pragma unroll
        for (int off = 32; off; off >>= 1) {
            s += __shfl_xor(s, off);
            nm = fmaxf(nm, __shfl_xor(nm, off));
        }
        if (lane == 0) {
            float neg = nm > -1e8f ? nm : 0.0f;
            int cnt = hist[c] - 1;
            float pos = cnt > 0 ? (s - 1.0f) / (float)cnt : 0.0f;
            acc += fmaxf(0.0f, MARGIN + neg - pos);
        }
    }
    __shared__ float sm[4];
    if (lane == 0) sm[w] = acc;
    __syncthreads();
    if (t == 0) lpart[blockIdx.x] = (sm[0] + sm[1]) + (sm[2] + sm[3]);
}

// ---------------- final scalar (sum 256 partials) ----------------
__global__ void k_out(const float* __restrict__ lpart, float* __restrict__ out) {
    int t = threadIdx.x;
    float v = lpart[t] + lpart[t + 64] + lpart[t + 128] + lpart[t + 192];
    #pragma unroll
    for (int off = 32; off; off >>= 1) v += __shfl_xor(v, off);
    if (t == 0) out[0] = v * (1.0f / (float)N_ROWS);
}

extern "C" void kernel_launch(void* const* d_in, const int* in_sizes, int n_in,
                              void* d_out, int out_size, void* d_ws, size_t ws_size,
                              hipStream_t stream) {
    const float* feat = (const float*)d_in[0];
    const int* lab    = (const int*)d_in[1];
    char* ws = (char*)d_ws;
    u16*      fb    = (u16*)ws;                                    // 2 MB
    float*    cs    = (float*)(ws + (2u << 20));                   // 256 KB
    float*    nbp   = (float*)(ws + (2u << 20) + (256u << 10));    // 2 MB [8192][64]
    int*      hist  = (int*)(ws + (4u << 20) + (256u << 10));      // 2 KB
    float*    lpart = (float*)(ws + (4u << 20) + (258u << 10));    // 1 KB
    float*    out   = (float*)d_out;

    k_prep2 <<<2560, 256, 0, stream>>>(feat, lab, fb, cs, hist);
    k_main  <<<2080, 512, 0, stream>>>(fb, lab, nbp);
    k_loss  <<<256,  256, 0, stream>>>(fb, cs, lab, nbp, hist, lpart);
    k_out   <<<1,    64,  0, stream>>>(lpart, out);
}